// Round 10
// baseline (105.926 us; speedup 1.0000x reference)
//
#include <hip/hip_runtime.h>
#include <math.h>
#include <stdint.h>

// SemiConv2d tropical conv: out = max_{ic,kh,kw} min(x_pad, K). f16-packed.
// R10: m97-style LDS staging. R2-R9 synthesis: stall ~30us regardless of
// per-lane load structure => memory-CONCURRENCY bound (Little's law:
// outstanding bytes/CU x ~600cyc L3 latency ~ 450GB/s, matching observed
// hbm_gbps). Fix: global_load_lds bulk staging (1KB/wave-instr, deep queue,
// ONE drain per 8-ic chunk at the barrier) + ds_read_b64 inner loop.
// Chunk = 8 ic x 10 rows x 48 uint2 = 30.7KB LDS, staged by exactly
// 10 dwordx4/thread (1920 = 10*192). K via s_load ("s" asm constraint --
// R8/R9 proved K path is neutral). Keep: 4-tap uint2 packing (R7), inline
// asm pk min/max, hp-fastest block order, -inf baked edges, 768 blocks.
// NOTE: ~58us of dur_us is fixed harness overhead (256MB ws poison fill
// ~46us + input restore + setup kernels).

#define HH 96
#define WW 96
#define CIN 32
#define OCN 32
#define XQ_ROWS 98
#define XQ_W 48
#define XQ_SLICE (XQ_ROWS * XQ_W)              // uint2 units per (n,ic) slice
#define XQ_TOTAL (256 * XQ_SLICE)              // uint2 elements
#define K2_TOTAL (8 * 32 * 4 * 9)              // uint32 elements
#define WS_NEED ((size_t)XQ_TOTAL * 8 + (size_t)K2_TOTAL * 4)
#define NEGH2 0xFC00FC00u

typedef _Float16 h2 __attribute__((ext_vector_type(2)));
typedef __attribute__((address_space(3))) uint32_t lds_u32;
typedef const __attribute__((address_space(1))) uint32_t glb_u32;

__device__ __forceinline__ uint32_t pkmin_vs(uint32_t x, uint32_t k) {
    uint32_t d;
    asm("v_pk_min_f16 %0, %1, %2" : "=v"(d) : "v"(x), "s"(k));
    return d;
}
__device__ __forceinline__ uint32_t pkmax(uint32_t a, uint32_t b) {
    uint32_t d;
    asm("v_pk_max_f16 %0, %1, %2" : "=v"(d) : "v"(a), "v"(b));
    return d;
}
__device__ __forceinline__ uint32_t packh2(float lo, float hi) {
    h2 p = {(_Float16)lo, (_Float16)hi};
    return __builtin_bit_cast(uint32_t, p);
}

// xq[(s*98 + rowpad)*48 + j] = 4xf16 (x[2j-1],x[2j] | x[2j+1],x[2j+2]), s=n*32+ic
__global__ __launch_bounds__(256) void setup_xq(const float* __restrict__ x,
                                                uint2* __restrict__ xq) {
    int idx = blockIdx.x * 256 + threadIdx.x;   // over 256*98*48 = 1,204,224
    int j  = idx % XQ_W;
    int t  = idx / XQ_W;
    int hp = t % XQ_ROWS;
    int s  = t / XQ_ROWS;
    int h  = hp - 1;
    bool hv = (h >= 0) && (h < HH);
    const float* row = x + ((size_t)s * HH + (hv ? h : 0)) * WW;
    float a = (hv && j > 0)        ? row[2 * j - 1] : -INFINITY;
    float b = hv                   ? row[2 * j]     : -INFINITY;
    float c = hv                   ? row[2 * j + 1] : -INFINITY;
    float d = (hv && j < XQ_W - 1) ? row[2 * j + 2] : -INFINITY;
    uint2 v;
    v.x = packh2(a, b);
    v.y = packh2(c, d);
    xq[idx] = v;
}

// k2[ocb][ic][oc][9] duplicated f16 pairs
__global__ __launch_bounds__(256) void setup_k(const float* __restrict__ kk,
                                               uint32_t* __restrict__ k2) {
    int idx = blockIdx.x * 256 + threadIdx.x;   // over 9216
    int tap  = idx % 9;
    int ocin = (idx / 9) % 4;
    int ic   = (idx / 36) % CIN;
    int ocb  = idx / (36 * CIN);
    float v = kk[(((ocb * 4 + ocin) * CIN) + ic) * 9 + tap];
    k2[idx] = packh2(v, v);
}

__global__ __launch_bounds__(192) void semiconv_f16_lds(const uint2* __restrict__ xq,
                                                        const uint32_t* __restrict__ k2,
                                                        float* __restrict__ out) {
    __shared__ uint2 xls[8 * 480];     // 8 ic x 10 rows x 48 j = 30720 B

    const int tid = threadIdx.x;
    const int jj = tid % 48;           // w-pair 0..47
    const int hr = tid / 48;           // 0..3
    const int b  = blockIdx.x;
    const int hp  = b % 12;            // hp FASTEST -> XCD L2 locality (R4 win)
    const int t   = b / 12;
    const int ocb = t & 7;
    const int n   = t >> 3;
    const int h0  = hp * 8;            // block covers output rows h0..h0+7
    const int hh  = h0 + 2 * hr;       // this thread: rows hh, hh+1

    const uint32_t* kp = k2 + (size_t)ocb * CIN * 36;

    uint32_t acc[4][2];
#pragma unroll
    for (int oc = 0; oc < 4; ++oc) { acc[oc][0] = NEGH2; acc[oc][1] = NEGH2; }

    // global base of this block's staged rows for ic=0: rows h0..h0+9 are
    // CONTIGUOUS within an ic-slice (480 uint2 = 3840 B = 240 uint4)
    const uintptr_t gbase = (uintptr_t)(xq + ((size_t)(n * CIN) * XQ_ROWS + h0) * XQ_W);
    const uintptr_t lbase = (uintptr_t)(&xls[0]);
    const uint32_t wave_u = (uint32_t)(tid & ~63) * 16;   // wave-uniform part

    for (int cc = 0; cc < 4; ++cc) {
        __syncthreads();               // protect xls reuse from previous chunk
#pragma unroll
        for (int r = 0; r < 10; ++r) { // 10*192 = 1920 dwordx4 = 30720 B
            int i   = r * 192 + tid;
            int icl = i / 240;         // which ic within chunk
            int off = i % 240;         // uint4 within the 3840B region
            glb_u32* gsrc = (glb_u32*)(gbase
                + ((size_t)(cc * 8 + icl) * XQ_SLICE) * 8 + (size_t)off * 16);
            lds_u32* ldst = (lds_u32*)(lbase + (uint32_t)(r * 192 * 16) + wave_u);
            __builtin_amdgcn_global_load_lds(gsrc, ldst, 16, 0, 0);
        }
        __syncthreads();               // drains vmcnt(0) then barrier (m97 pattern)

        const uint2* xl = xls + 96 * hr + jj;
#pragma unroll
        for (int u = 0; u < 8; ++u) {
            const uint2* xr = xl + u * 480;
            uint2 w0 = xr[0], w1 = xr[48], w2 = xr[96], w3 = xr[144];
            uint32_t xt[4][3];
            xt[0][0] = w0.x; xt[0][1] = __builtin_amdgcn_alignbit(w0.y, w0.x, 16); xt[0][2] = w0.y;
            xt[1][0] = w1.x; xt[1][1] = __builtin_amdgcn_alignbit(w1.y, w1.x, 16); xt[1][2] = w1.y;
            xt[2][0] = w2.x; xt[2][1] = __builtin_amdgcn_alignbit(w2.y, w2.x, 16); xt[2][2] = w2.y;
            xt[3][0] = w3.x; xt[3][1] = __builtin_amdgcn_alignbit(w3.y, w3.x, 16); xt[3][2] = w3.y;

            const uint32_t* kq0 = kp + (cc * 8 + u) * 36;
#pragma unroll
            for (int oc = 0; oc < 4; ++oc) {
                const uint32_t* kq = kq0 + oc * 9;       // uniform -> s_load
#pragma unroll
                for (int o = 0; o < 2; ++o) {
                    uint32_t m0 = pkmin_vs(xt[o][0],     kq[0]);
                    uint32_t m1 = pkmin_vs(xt[o][1],     kq[1]);
                    uint32_t m2 = pkmin_vs(xt[o][2],     kq[2]);
                    uint32_t m3 = pkmin_vs(xt[o + 1][0], kq[3]);
                    uint32_t m4 = pkmin_vs(xt[o + 1][1], kq[4]);
                    uint32_t m5 = pkmin_vs(xt[o + 1][2], kq[5]);
                    uint32_t m6 = pkmin_vs(xt[o + 2][0], kq[6]);
                    uint32_t m7 = pkmin_vs(xt[o + 2][1], kq[7]);
                    uint32_t m8 = pkmin_vs(xt[o + 2][2], kq[8]);
                    uint32_t t01 = pkmax(m0, m1), t23 = pkmax(m2, m3);
                    uint32_t t45 = pkmax(m4, m5), t67 = pkmax(m6, m7);
                    uint32_t tt  = pkmax(pkmax(t01, t23), pkmax(t45, t67));
                    acc[oc][o] = pkmax(acc[oc][o], pkmax(tt, m8));
                }
            }
        }
    }

#pragma unroll
    for (int oc = 0; oc < 4; ++oc)
#pragma unroll
        for (int o = 0; o < 2; ++o) {
            h2 a = __builtin_bit_cast(h2, acc[oc][o]);
            float2 v = make_float2((float)a.x, (float)a.y);
            *(float2*)(out + (((size_t)(n * OCN + ocb * 4 + oc)) * HH + hh + o) * WW + 2 * jj) = v;
        }
}

// ---------- f32 fallback if ws is too small ----------
#define NEGINF (-INFINITY)
__global__ __launch_bounds__(192, 8) void semiconv2d_f32(
    const float* __restrict__ x, const float* __restrict__ kk, float* __restrict__ out)
{
    const int tid = threadIdx.x;
    const int w  = tid % WW;
    const int hr = tid / WW;
    const int b   = blockIdx.x;
    const int ocb = b & 7;
    const int hp  = (b >> 3) % 48;
    const int n   = (b >> 3) / 48;
    const int h   = hp * 2 + hr;
    const int oc0 = ocb * 4;
    float a0[4], a1[4], a2[4];
#pragma unroll
    for (int i = 0; i < 4; ++i) { a0[i] = NEGINF; a1[i] = NEGINF; a2[i] = NEGINF; }
    const bool vm = (h > 0), vp = (h < HH - 1);
    const int hm  = vm ? h - 1 : h;
    const int hpl = vp ? h + 1 : h;
    const int cm  = (w > 0) ? -1 : 0;
    const int cp  = (w < WW - 1) ? 1 : 0;
    const float* rm = x + ((size_t)(n * CIN) * HH + hm)  * WW + w;
    const float* r1 = x + ((size_t)(n * CIN) * HH + h)   * WW + w;
    const float* rp = x + ((size_t)(n * CIN) * HH + hpl) * WW + w;
#pragma unroll 2
    for (int ic = 0; ic < CIN; ++ic) {
        float r00 = vm ? rm[cm] : NEGINF, r01 = vm ? rm[0] : NEGINF, r02 = vm ? rm[cp] : NEGINF;
        float r10 = r1[cm], r11 = r1[0], r12 = r1[cp];
        float r20 = vp ? rp[cm] : NEGINF, r21 = vp ? rp[0] : NEGINF, r22 = vp ? rp[cp] : NEGINF;
#pragma unroll
        for (int oc = 0; oc < 4; ++oc) {
            const float* kq = kk + (size_t)(((oc0 + oc) * CIN + ic)) * 9;
            a0[oc] = fmaxf(fmaxf(a0[oc], fminf(r00, kq[0])), fmaxf(fminf(r10, kq[3]), fminf(r20, kq[6])));
            a1[oc] = fmaxf(fmaxf(a1[oc], fminf(r01, kq[1])), fmaxf(fminf(r11, kq[4]), fminf(r21, kq[7])));
            a2[oc] = fmaxf(fmaxf(a2[oc], fminf(r02, kq[2])), fmaxf(fminf(r12, kq[5]), fminf(r22, kq[8])));
        }
        rm += HH * WW; r1 += HH * WW; rp += HH * WW;
    }
#pragma unroll
    for (int oc = 0; oc < 4; ++oc) {
        float v0 = (w > 0)      ? a0[oc] : NEGINF;
        float v2 = (w < WW - 1) ? a2[oc] : NEGINF;
        out[(((size_t)(n * OCN + oc0 + oc)) * HH + h) * WW + w] = fmaxf(fmaxf(v0, a1[oc]), v2);
    }
}

extern "C" void kernel_launch(void* const* d_in, const int* in_sizes, int n_in,
                              void* d_out, int out_size, void* d_ws, size_t ws_size,
                              hipStream_t stream) {
    const float* x  = (const float*)d_in[0];
    const float* kk = (const float*)d_in[1];
    float* out      = (float*)d_out;
    if (ws_size >= WS_NEED) {
        uint2* xq    = (uint2*)d_ws;
        uint32_t* k2 = (uint32_t*)(xq + XQ_TOTAL);
        setup_xq<<<dim3(XQ_TOTAL / 256), dim3(256), 0, stream>>>(x, xq);
        setup_k<<<dim3(K2_TOTAL / 256), dim3(256), 0, stream>>>(kk, k2);
        semiconv_f16_lds<<<dim3(8 * 8 * 12), dim3(192), 0, stream>>>(xq, k2, out);
    } else {
        semiconv2d_f32<<<dim3(8 * 48 * 8), dim3(192), 0, stream>>>(x, kk, out);
    }
}